// Round 1
// baseline (368.527 us; speedup 1.0000x reference)
//
#include <hip/hip_runtime.h>
#include <hip/hip_bf16.h>

#define D_FEAT 32

// ---------------------------------------------------------------------------
// K0: per-node inverse L2 norm. 32 lanes cooperate per node.
// ---------------------------------------------------------------------------
__global__ void node_invnorm_kernel(const float* __restrict__ feat,
                                    float* __restrict__ inv_norm, int n_nodes) {
    int g = blockIdx.x * blockDim.x + threadIdx.x;
    int node = g >> 5;
    int lane = g & 31;
    if (node >= n_nodes) return;
    float v = feat[node * D_FEAT + lane];
    float ss = v * v;
    #pragma unroll
    for (int m = 16; m; m >>= 1) ss += __shfl_xor(ss, m, 32);
    if (lane == 0) {
        float nrm = sqrtf(ss);
        nrm = fmaxf(nrm, 1e-12f);
        inv_norm[node] = 1.0f / nrm;
    }
}

// ---------------------------------------------------------------------------
// K1: per-edge un-normalized softmax weight p_e = exp(beta * cos(u,v)),
//     and segment-sum of p into s[dst] via atomics.
//     32 lanes per edge; coalesced 128B reads of each feature row.
// ---------------------------------------------------------------------------
__global__ void edge_p_kernel(const float* __restrict__ feat,
                              const float* __restrict__ inv_norm,
                              const int* __restrict__ src,
                              const int* __restrict__ dst,
                              const float* __restrict__ beta,
                              float* __restrict__ p,
                              float* __restrict__ s,
                              int n_edges) {
    int g = blockIdx.x * blockDim.x + threadIdx.x;
    int e = g >> 5;
    int lane = g & 31;
    if (e >= n_edges) return;
    int u = src[e];
    int v = dst[e];
    float a = feat[u * D_FEAT + lane];
    float b = feat[v * D_FEAT + lane];
    float d = a * b;
    #pragma unroll
    for (int m = 16; m; m >>= 1) d += __shfl_xor(d, m, 32);
    if (lane == 0) {
        float e_val = beta[0] * d * inv_norm[u] * inv_norm[v];
        float pe = expf(e_val);   // e in [-beta, beta]; no overflow, max shift skipped
        p[e] = pe;
        atomicAdd(&s[v], pe);
    }
}

// ---------------------------------------------------------------------------
// K2: out[dst] += feat[src] * (p_e / s[dst]), scatter with f32 atomics.
// ---------------------------------------------------------------------------
__global__ void aggregate_kernel(const float* __restrict__ feat,
                                 const int* __restrict__ src,
                                 const int* __restrict__ dst,
                                 const float* __restrict__ p,
                                 const float* __restrict__ s,
                                 float* __restrict__ out,
                                 int n_edges) {
    int g = blockIdx.x * blockDim.x + threadIdx.x;
    int e = g >> 5;
    int lane = g & 31;
    if (e >= n_edges) return;
    int u = src[e];
    int v = dst[e];
    float w = p[e] / s[v];
    atomicAdd(&out[v * D_FEAT + lane], feat[u * D_FEAT + lane] * w);
}

extern "C" void kernel_launch(void* const* d_in, const int* in_sizes, int n_in,
                              void* d_out, int out_size, void* d_ws, size_t ws_size,
                              hipStream_t stream) {
    const float* feat = (const float*)d_in[0];
    const float* beta = (const float*)d_in[1];
    const int*   src  = (const int*)d_in[2];
    const int*   dst  = (const int*)d_in[3];
    float* out = (float*)d_out;

    int n_nodes = in_sizes[0] / D_FEAT;
    int n_edges = in_sizes[2];

    // workspace layout: inv_norm [n_nodes] | s [n_nodes] | p [n_edges]
    float* inv_norm = (float*)d_ws;
    float* s_sum    = inv_norm + n_nodes;
    float* p        = s_sum + n_nodes;

    // zero the softmax denominators and the output accumulator
    hipMemsetAsync(s_sum, 0, (size_t)n_nodes * sizeof(float), stream);
    hipMemsetAsync(out, 0, (size_t)out_size * sizeof(float), stream);

    {
        int total = n_nodes * D_FEAT;
        int blocks = (total + 255) / 256;
        node_invnorm_kernel<<<blocks, 256, 0, stream>>>(feat, inv_norm, n_nodes);
    }
    {
        long long total = (long long)n_edges * 32;
        int blocks = (int)((total + 255) / 256);
        edge_p_kernel<<<blocks, 256, 0, stream>>>(feat, inv_norm, src, dst, beta,
                                                  p, s_sum, n_edges);
    }
    {
        long long total = (long long)n_edges * 32;
        int blocks = (int)((total + 255) / 256);
        aggregate_kernel<<<blocks, 256, 0, stream>>>(feat, src, dst, p, s_sum,
                                                     out, n_edges);
    }
}